// Round 3
// baseline (330.592 us; speedup 1.0000x reference)
//
#include <hip/hip_runtime.h>

// GraphConv: out = relu( D * A_hat * D * x * W ),  B=8, N=2048, F=O=128, fp32.
// R8: three kernels, all occupancy-tuned.
//  K1 d_kernel : rowsum d, 1 wave/row, 4096 blocks (16/CU, no LDS) + 64 tail
//                blocks convert Wt=bf16(W^T).  (R5's proven layout.)
//  K2 xw_kernel: yt[b][o][m] = bf16((x@W)[m,o]) UNSCALED, 256 blocks, global Wt.
//  K3 gemm     : barrier-free direct-load GEMM, 16-row tiles -> grid 1024
//                (4 blocks/CU = 16 waves/CU, 2x R7's TLP). d[m] folded into
//                the A-frag convert; d[n] + diag correction in epilogue.
//                R7 evidence: 98us @ 817GB/s, MfmaUtil 3.3%, Occ 20% =
//                latency-bound at 2 blocks/CU. This doubles resident waves
//                and shortens the per-iter dep chain (2 MFMA, 6 loads).

typedef __bf16 bf16x8 __attribute__((ext_vector_type(8)));
typedef float  f32x4  __attribute__((ext_vector_type(4)));

#define NN 2048
#define NB 8

// ---------------- K1: degree vector + Wt convert in tail blocks ----------
__global__ __launch_bounds__(256) void d_kernel(const float* __restrict__ adj,
                                                float* __restrict__ dvec,
                                                const float* __restrict__ W,
                                                __bf16* __restrict__ Wt) {
    if (blockIdx.x >= NB * NN / 4) {
        // tail: Wt[o][f] = bf16(W[f][o]),  64 blocks x 256 thr = 16384
        int idx = (blockIdx.x - NB * NN / 4) * 256 + threadIdx.x;
        int f = idx >> 7, o = idx & 127;
        Wt[o * 128 + f] = (__bf16)W[idx];
        return;
    }
    const int lane = threadIdx.x & 63;
    const int row  = blockIdx.x * 4 + (threadIdx.x >> 6);   // one wave per row
    const float* rp = adj + (size_t)row * NN;
    float4 s4 = {0.f, 0.f, 0.f, 0.f};
#pragma unroll
    for (int it = 0; it < 8; ++it) {
        float4 v = *(const float4*)(rp + it * 256 + lane * 4);
        s4.x += v.x; s4.y += v.y; s4.z += v.z; s4.w += v.w;
    }
    float s = (s4.x + s4.y) + (s4.z + s4.w);
#pragma unroll
    for (int off = 32; off; off >>= 1) s += __shfl_down(s, off);
    if (lane == 0) {
        int n = row & (NN - 1);
        float sh = s - rp[n] + 1.0f;            // zero diag, add self-loop
        dvec[row] = 1.0f / (1e-6f + sqrtf(sh));
    }
}

// ---------------- K2: yt[b][o][m] = bf16((x@W)[m,o]), LDS-free, unscaled --
__global__ __launch_bounds__(256) void xw_kernel(const float* __restrict__ x,
                                                 const __bf16* __restrict__ Wt,
                                                 __bf16* __restrict__ yt) {
    const int lane = threadIdx.x & 63;
    const int wave = threadIdx.x >> 6;
    const int b    = blockIdx.x & 7;
    const int mt   = (blockIdx.x >> 3) * 4 + wave;   // 0..127
    const int m0   = mt * 16;
    const int kgrp = (lane >> 4) * 8;
    const float* xp = x + ((size_t)b * NN + m0 + (lane & 15)) * 128 + kgrp;

    f32x4 acc[8];
#pragma unroll
    for (int i = 0; i < 8; ++i) acc[i] = (f32x4){0.f, 0.f, 0.f, 0.f};

#pragma unroll
    for (int kt = 0; kt < 4; ++kt) {
        f32x4 a0 = *(const f32x4*)(xp + kt * 32);
        f32x4 a1 = *(const f32x4*)(xp + kt * 32 + 4);
        float av[8] = {a0.x, a0.y, a0.z, a0.w, a1.x, a1.y, a1.z, a1.w};
        bf16x8 af;
#pragma unroll
        for (int j = 0; j < 8; ++j) af[j] = (__bf16)av[j];
#pragma unroll
        for (int nb = 0; nb < 8; ++nb) {
            bf16x8 bfv = *(const bf16x8*)(Wt + (nb * 16 + (lane & 15)) * 128 +
                                          kt * 32 + kgrp);
            acc[nb] = __builtin_amdgcn_mfma_f32_16x16x32_bf16(af, bfv, acc[nb], 0, 0, 0);
        }
    }
    const int col0 = lane & 15;
    const int rq   = (lane >> 4) * 4;
#pragma unroll
    for (int r = 0; r < 4; ++r) {
        int m = m0 + rq + r;
#pragma unroll
        for (int nb = 0; nb < 8; ++nb) {
            int o = nb * 16 + col0;
            yt[((size_t)b * 128 + o) * NN + m] = (__bf16)acc[nb][r];
        }
    }
}

// ---------------- K3: barrier-free direct-load GEMM, 16-row tiles ---------
// Block 256 thr = 4 waves: tile = 16 rows x 128 cols; wave w: cols w*32.
// grid 1024 (4 blocks/CU), b = blockIdx.x & 7.  NO LDS, NO __syncthreads.
__global__ __launch_bounds__(256) void gemm_kernel(const float* __restrict__ adj,
                                                   const __bf16* __restrict__ yt,
                                                   const float* __restrict__ dvec,
                                                   float* __restrict__ out) {
    const int tid  = threadIdx.x;
    const int wave = tid >> 6;
    const int lane = tid & 63;
    const int b    = blockIdx.x & 7;
    const int tile = blockIdx.x >> 3;            // 0..127
    const int csel = wave * 32;
    const int kgrp = (lane >> 4) * 8;

    // A: adj fp32, 16 rows (lane&15) strided 8 KB, k-contiguous 32 B/lane.
    // All 4 waves load the same A/d addresses -> L1 broadcast after first.
    const int arow_loc = tile * 16 + (lane & 15);
    const float* ap = adj + ((size_t)b * NN + arow_loc) * NN + kgrp;
    const float* dp = dvec + b * NN + kgrp;

    // B: yt bf16, rows csel+(lane&15) strided 4 KB, 16 B/lane (L2-resident).
    const __bf16* ytb = yt + (size_t)b * 128 * NN;
    const __bf16* bp  = ytb + (size_t)(csel + (lane & 15)) * NN + kgrp;

    f32x4 acc[2];
#pragma unroll
    for (int i = 0; i < 2; ++i) acc[i] = (f32x4){0.f, 0.f, 0.f, 0.f};

#pragma unroll 4
    for (int kt = 0; kt < 64; ++kt) {
        const int ko = kt * 32;
        f32x4 a0 = *(const f32x4*)(ap + ko);
        f32x4 a1 = *(const f32x4*)(ap + ko + 4);
        f32x4 d0 = *(const f32x4*)(dp + ko);
        f32x4 d1 = *(const f32x4*)(dp + ko + 4);

        // A-frag = bf16( adj[n,m] * d[m] ) — fp32 multiply, single rounding
        bf16x8 af;
        af[0] = (__bf16)(a0.x * d0.x); af[1] = (__bf16)(a0.y * d0.y);
        af[2] = (__bf16)(a0.z * d0.z); af[3] = (__bf16)(a0.w * d0.w);
        af[4] = (__bf16)(a1.x * d1.x); af[5] = (__bf16)(a1.y * d1.y);
        af[6] = (__bf16)(a1.z * d1.z); af[7] = (__bf16)(a1.w * d1.w);

#pragma unroll
        for (int nb = 0; nb < 2; ++nb) {
            bf16x8 bfv = *(const bf16x8*)(bp + (size_t)(nb * 16) * NN + ko);
            acc[nb] = __builtin_amdgcn_mfma_f32_16x16x32_bf16(af, bfv, acc[nb], 0, 0, 0);
        }
    }

    // epilogue: out = d[n] * (acc + (1 - adj[n,n]) * d[n] * yt[o][n]), relu
    const int col0 = lane & 15;
    const int rq   = (lane >> 4) * 4;
#pragma unroll
    for (int r = 0; r < 4; ++r) {
        int n_loc = tile * 16 + rq + r;
        size_t grow = (size_t)b * NN + n_loc;
        float dn   = dvec[grow];
        float cfac = (1.0f - adj[grow * NN + n_loc]) * dn;
#pragma unroll
        for (int nb = 0; nb < 2; ++nb) {
            int o = csel + nb * 16 + col0;
            float yp = (float)ytb[(size_t)o * NN + n_loc];
            float v = (acc[nb][r] + cfac * yp) * dn;
            out[grow * 128 + o] = v > 0.f ? v : 0.f;
        }
    }
}

extern "C" void kernel_launch(void* const* d_in, const int* in_sizes, int n_in,
                              void* d_out, int out_size, void* d_ws, size_t ws_size,
                              hipStream_t stream) {
    const float* x   = (const float*)d_in[0];   // [8,2048,128]
    const float* adj = (const float*)d_in[1];   // [8,2048,2048]
    const float* W   = (const float*)d_in[2];   // [128,128]
    float* out = (float*)d_out;

    char* ws = (char*)d_ws;
    float*  dvec = (float*)ws;                          // 64 KB
    __bf16* Wt   = (__bf16*)(ws + (64 << 10));          // 32 KB
    __bf16* yt   = (__bf16*)(ws + (128 << 10));         // 4 MB  [B][128][2048]

    hipLaunchKernelGGL(d_kernel, dim3(NB * NN / 4 + 64), dim3(256), 0, stream,
                       adj, dvec, W, Wt);
    hipLaunchKernelGGL(xw_kernel, dim3(256), dim3(256), 0, stream, x, Wt, yt);
    hipLaunchKernelGGL(gemm_kernel, dim3(1024), dim3(256), 0, stream,
                       adj, yt, dvec, out);
}

// Round 4
// 246.512 us; speedup vs baseline: 1.3411x; 1.3411x over previous
//
#include <hip/hip_runtime.h>

// GraphConv: out = relu( D * A_hat * D * x * W ),  B=8, N=2048, F=O=128, fp32.
// R9: R5 base (best known, 244.2us) with ONE change: K3's per-iter
//     __syncthreads() (vmcnt(0)+lgkmcnt(0) drain, 64x) replaced by a
//     counted-vmcnt barrier (T4): s_waitcnt vmcnt(2) + raw s_barrier, with
//     sched_barrier(0) pinning issue order glds -> A-loads so the in-order
//     vmcnt count is exact. Next iter's 2 glds + 2 A-loads stay in flight
//     across the barrier instead of being drained to zero.
// Evidence: R7/R8 proved de-staging is request-duplication-bound (4 waves
// re-loading the same A rows, 595-817 GB/s, MfmaUtil ~3%); R5's staged K3
// (~52us inferred) is the best structure, limited by its barrier drain.

typedef __bf16 bf16x8 __attribute__((ext_vector_type(8)));
typedef float  f32x4  __attribute__((ext_vector_type(4)));

#define NN 2048
#define NB 8

__device__ __forceinline__ void load_lds16(__bf16* lds, const __bf16* g) {
    // per-lane global src; LDS dest = wave-uniform base + lane*16
    __builtin_amdgcn_global_load_lds(
        (const __attribute__((address_space(1))) void*)g,
        (__attribute__((address_space(3))) void*)lds, 16, 0, 0);
}

// ---------------- K1: degree vector + Wt convert in tail blocks ----------
__global__ __launch_bounds__(256) void d_kernel(const float* __restrict__ adj,
                                                float* __restrict__ dvec,
                                                const float* __restrict__ W,
                                                __bf16* __restrict__ Wt) {
    if (blockIdx.x >= NB * NN / 4) {
        // tail: Wt[o][f] = bf16(W[f][o]),  64 blocks x 256 thr = 16384
        int idx = (blockIdx.x - NB * NN / 4) * 256 + threadIdx.x;
        int f = idx >> 7, o = idx & 127;
        Wt[o * 128 + f] = (__bf16)W[idx];
        return;
    }
    const int lane = threadIdx.x & 63;
    const int row  = blockIdx.x * 4 + (threadIdx.x >> 6);   // one wave per row
    const float* rp = adj + (size_t)row * NN;
    float4 s4 = {0.f, 0.f, 0.f, 0.f};
#pragma unroll
    for (int it = 0; it < 8; ++it) {
        float4 v = *(const float4*)(rp + it * 256 + lane * 4);
        s4.x += v.x; s4.y += v.y; s4.z += v.z; s4.w += v.w;
    }
    float s = (s4.x + s4.y) + (s4.z + s4.w);
#pragma unroll
    for (int off = 32; off; off >>= 1) s += __shfl_down(s, off);
    if (lane == 0) {
        int n = row & (NN - 1);
        float sh = s - rp[n] + 1.0f;            // zero diag, add self-loop
        dvec[row] = 1.0f / (1e-6f + sqrtf(sh));
    }
}

// ---------------- K2: yt[b][o][m] = bf16(d[m] * (x@W)[m,o]), LDS-free ----
__global__ __launch_bounds__(256) void xw_kernel(const float* __restrict__ x,
                                                 const __bf16* __restrict__ Wt,
                                                 const float* __restrict__ dvec,
                                                 __bf16* __restrict__ yt) {
    const int lane = threadIdx.x & 63;
    const int wave = threadIdx.x >> 6;
    const int b    = blockIdx.x & 7;
    const int mt   = (blockIdx.x >> 3) * 4 + wave;   // 0..127
    const int m0   = mt * 16;
    const int kgrp = (lane >> 4) * 8;
    const float* xp = x + ((size_t)b * NN + m0 + (lane & 15)) * 128 + kgrp;

    f32x4 acc[8];
#pragma unroll
    for (int i = 0; i < 8; ++i) acc[i] = (f32x4){0.f, 0.f, 0.f, 0.f};

#pragma unroll
    for (int kt = 0; kt < 4; ++kt) {
        f32x4 a0 = *(const f32x4*)(xp + kt * 32);
        f32x4 a1 = *(const f32x4*)(xp + kt * 32 + 4);
        float av[8] = {a0.x, a0.y, a0.z, a0.w, a1.x, a1.y, a1.z, a1.w};
        bf16x8 af;
#pragma unroll
        for (int j = 0; j < 8; ++j) af[j] = (__bf16)av[j];
#pragma unroll
        for (int nb = 0; nb < 8; ++nb) {
            bf16x8 bfv = *(const bf16x8*)(Wt + (nb * 16 + (lane & 15)) * 128 +
                                          kt * 32 + kgrp);
            acc[nb] = __builtin_amdgcn_mfma_f32_16x16x32_bf16(af, bfv, acc[nb], 0, 0, 0);
        }
    }
    const int col0 = lane & 15;
    const int rq   = (lane >> 4) * 4;
#pragma unroll
    for (int r = 0; r < 4; ++r) {
        int m = m0 + rq + r;
        float dm = dvec[b * NN + m];
#pragma unroll
        for (int nb = 0; nb < 8; ++nb) {
            int o = nb * 16 + col0;
            yt[((size_t)b * 128 + o) * NN + m] = (__bf16)(acc[nb][r] * dm);
        }
    }
}

// ---------------- K3: direct-A GEMM with counted-vmcnt barrier -----------
// Block 256 thr: 32 rows x 128 cols; wave w: rows (w&1)*16, cols (w>>1)*64.
// grid 512 (2 blocks/CU), b = blockIdx.x & 7.
__global__ __launch_bounds__(256) void gemm_kernel(const float* __restrict__ adj,
                                                   const __bf16* __restrict__ yt,
                                                   const float* __restrict__ dvec,
                                                   float* __restrict__ out) {
    __shared__ alignas(16) __bf16 sB[2][128][32];

    const int tid  = threadIdx.x;
    const int wave = tid >> 6;
    const int lane = tid & 63;
    const int b    = blockIdx.x & 7;
    const int tile = blockIdx.x >> 3;            // 0..63
    const int rsel = (wave & 1) * 16;
    const int csel = (wave >> 1) * 64;
    const int kgrp = (lane >> 4) * 8;

    // A: direct from global fp32, k-contiguous fragment
    const int arow_loc = tile * 32 + rsel + (lane & 15);
    const float* ap = adj + ((size_t)b * NN + arow_loc) * NN + kgrp;

    const __bf16* ytb = yt + (size_t)b * 128 * NN;
    const int b_row0 = wave * 32;
    const __bf16* b_src = ytb + (size_t)(b_row0 + (lane >> 2)) * NN + (lane & 3) * 8;

    f32x4 acc[4];
#pragma unroll
    for (int i = 0; i < 4; ++i) acc[i] = (f32x4){0.f, 0.f, 0.f, 0.f};

    // preload iter 0: glds FIRST (vmcnt is in-order; count relies on this)
    load_lds16(&sB[0][b_row0][0], b_src);
    load_lds16(&sB[0][b_row0 + 16][0], b_src + (size_t)16 * NN);
    __builtin_amdgcn_sched_barrier(0);
    f32x4 ca0 = *(const f32x4*)(ap);
    f32x4 ca1 = *(const f32x4*)(ap + 4);

    for (int kt = 0; kt < 64; ++kt) {
        const int cur = kt & 1;
        // Outstanding VMEM at this point (issue order): 2 glds for buf[cur],
        // then 2 A-loads for this iter. vmcnt(2) completes the glds (oldest
        // first, in-order) and leaves the A-loads in flight; the compiler's
        // own vmcnt before the cvt covers them. Barrier publishes sB[cur].
        asm volatile("s_waitcnt vmcnt(2)" ::: "memory");
        __builtin_amdgcn_sched_barrier(0);
        __builtin_amdgcn_s_barrier();
        __builtin_amdgcn_sched_barrier(0);

        f32x4 na0, na1;
        if (kt + 1 < 64) {
            const __bf16* bs = b_src + (size_t)(kt + 1) * 32;
            load_lds16(&sB[cur ^ 1][b_row0][0], bs);
            load_lds16(&sB[cur ^ 1][b_row0 + 16][0], bs + (size_t)16 * NN);
            __builtin_amdgcn_sched_barrier(0);   // pin: glds issue BEFORE A-loads
            na0 = *(const f32x4*)(ap + (kt + 1) * 32);
            na1 = *(const f32x4*)(ap + (kt + 1) * 32 + 4);
        }

        // convert current A regs (loaded last iter; compiler-inserted vmcnt)
        bf16x8 af;
        af[0] = (__bf16)ca0.x; af[1] = (__bf16)ca0.y;
        af[2] = (__bf16)ca0.z; af[3] = (__bf16)ca0.w;
        af[4] = (__bf16)ca1.x; af[5] = (__bf16)ca1.y;
        af[6] = (__bf16)ca1.z; af[7] = (__bf16)ca1.w;

#pragma unroll
        for (int nb = 0; nb < 4; ++nb) {
            bf16x8 bfv = *(const bf16x8*)(
                &sB[cur][csel + nb * 16 + (lane & 15)][kgrp]);
            acc[nb] = __builtin_amdgcn_mfma_f32_16x16x32_bf16(af, bfv, acc[nb], 0, 0, 0);
        }
        ca0 = na0; ca1 = na1;
    }

    // epilogue: diag correction + row scale + relu
    //   out = d[n] * (acc + (1 - adj[n,n]) * yt[o][n])
    const int col0 = lane & 15;
    const int rq   = (lane >> 4) * 4;
#pragma unroll
    for (int r = 0; r < 4; ++r) {
        int n_loc = tile * 32 + rsel + rq + r;
        size_t grow = (size_t)b * NN + n_loc;
        float dn   = dvec[grow];
        float cfac = 1.0f - adj[grow * NN + n_loc];
#pragma unroll
        for (int nb = 0; nb < 4; ++nb) {
            int o = csel + nb * 16 + col0;
            float yp = (float)ytb[(size_t)o * NN + n_loc];
            float v = (acc[nb][r] + cfac * yp) * dn;
            out[grow * 128 + o] = v > 0.f ? v : 0.f;
        }
    }
}

extern "C" void kernel_launch(void* const* d_in, const int* in_sizes, int n_in,
                              void* d_out, int out_size, void* d_ws, size_t ws_size,
                              hipStream_t stream) {
    const float* x   = (const float*)d_in[0];   // [8,2048,128]
    const float* adj = (const float*)d_in[1];   // [8,2048,2048]
    const float* W   = (const float*)d_in[2];   // [128,128]
    float* out = (float*)d_out;

    char* ws = (char*)d_ws;
    float*  dvec = (float*)ws;                          // 64 KB
    __bf16* Wt   = (__bf16*)(ws + (64 << 10));          // 32 KB
    __bf16* yt   = (__bf16*)(ws + (128 << 10));         // 4 MB  [B][128][2048]

    hipLaunchKernelGGL(d_kernel, dim3(NB * NN / 4 + 64), dim3(256), 0, stream,
                       adj, dvec, W, Wt);
    hipLaunchKernelGGL(xw_kernel, dim3(256), dim3(256), 0, stream, x, Wt, dvec, yt);
    hipLaunchKernelGGL(gemm_kernel, dim3(512), dim3(256), 0, stream,
                       adj, yt, dvec, out);
}

// Round 5
// 244.672 us; speedup vs baseline: 1.3512x; 1.0075x over previous
//
#include <hip/hip_runtime.h>

// GraphConv: out = relu( D * A_hat * D * x * W ),  B=8, N=2048, F=O=128, fp32.
// R10: R5 base; K3 pipeline deepened to 3 tiles in flight (T3/T4 proper dose).
//   4 LDS buffers; body kt: wait vmcnt(6) [completes G(kt)+A(kt)], barrier,
//   ds_read buf[kt&3], cvt A(kt), issue A(kt+2), issue G(kt+3), 4x MFMA.
//   Steady outstanding = 10 vmem ops (3 glds pairs + 2 A pairs); tail peels
//   waits 6/6/4/0. R9's depth-1 counted wait was neutral because the wait
//   covered loads issued only ~150cyc earlier; depth-3 gives ~450-600cyc.
// K1/K2 unchanged (R5 proven): d 1-wave/row + Wt tail; xw LDS-free MFMA.

typedef __bf16 bf16x8 __attribute__((ext_vector_type(8)));
typedef float  f32x4  __attribute__((ext_vector_type(4)));

#define NN 2048
#define NB 8

__device__ __forceinline__ void load_lds16(__bf16* lds, const __bf16* g) {
    // per-lane global src; LDS dest = wave-uniform base + lane*16
    __builtin_amdgcn_global_load_lds(
        (const __attribute__((address_space(1))) void*)g,
        (__attribute__((address_space(3))) void*)lds, 16, 0, 0);
}

// ---------------- K1: degree vector + Wt convert in tail blocks ----------
__global__ __launch_bounds__(256) void d_kernel(const float* __restrict__ adj,
                                                float* __restrict__ dvec,
                                                const float* __restrict__ W,
                                                __bf16* __restrict__ Wt) {
    if (blockIdx.x >= NB * NN / 4) {
        int idx = (blockIdx.x - NB * NN / 4) * 256 + threadIdx.x;
        int f = idx >> 7, o = idx & 127;
        Wt[o * 128 + f] = (__bf16)W[idx];
        return;
    }
    const int lane = threadIdx.x & 63;
    const int row  = blockIdx.x * 4 + (threadIdx.x >> 6);   // one wave per row
    const float* rp = adj + (size_t)row * NN;
    float4 s4 = {0.f, 0.f, 0.f, 0.f};
#pragma unroll
    for (int it = 0; it < 8; ++it) {
        float4 v = *(const float4*)(rp + it * 256 + lane * 4);
        s4.x += v.x; s4.y += v.y; s4.z += v.z; s4.w += v.w;
    }
    float s = (s4.x + s4.y) + (s4.z + s4.w);
#pragma unroll
    for (int off = 32; off; off >>= 1) s += __shfl_down(s, off);
    if (lane == 0) {
        int n = row & (NN - 1);
        float sh = s - rp[n] + 1.0f;            // zero diag, add self-loop
        dvec[row] = 1.0f / (1e-6f + sqrtf(sh));
    }
}

// ---------------- K2: yt[b][o][m] = bf16(d[m] * (x@W)[m,o]), LDS-free ----
__global__ __launch_bounds__(256) void xw_kernel(const float* __restrict__ x,
                                                 const __bf16* __restrict__ Wt,
                                                 const float* __restrict__ dvec,
                                                 __bf16* __restrict__ yt) {
    const int lane = threadIdx.x & 63;
    const int wave = threadIdx.x >> 6;
    const int b    = blockIdx.x & 7;
    const int mt   = (blockIdx.x >> 3) * 4 + wave;   // 0..127
    const int m0   = mt * 16;
    const int kgrp = (lane >> 4) * 8;
    const float* xp = x + ((size_t)b * NN + m0 + (lane & 15)) * 128 + kgrp;

    f32x4 acc[8];
#pragma unroll
    for (int i = 0; i < 8; ++i) acc[i] = (f32x4){0.f, 0.f, 0.f, 0.f};

#pragma unroll
    for (int kt = 0; kt < 4; ++kt) {
        f32x4 a0 = *(const f32x4*)(xp + kt * 32);
        f32x4 a1 = *(const f32x4*)(xp + kt * 32 + 4);
        float av[8] = {a0.x, a0.y, a0.z, a0.w, a1.x, a1.y, a1.z, a1.w};
        bf16x8 af;
#pragma unroll
        for (int j = 0; j < 8; ++j) af[j] = (__bf16)av[j];
#pragma unroll
        for (int nb = 0; nb < 8; ++nb) {
            bf16x8 bfv = *(const bf16x8*)(Wt + (nb * 16 + (lane & 15)) * 128 +
                                          kt * 32 + kgrp);
            acc[nb] = __builtin_amdgcn_mfma_f32_16x16x32_bf16(af, bfv, acc[nb], 0, 0, 0);
        }
    }
    const int col0 = lane & 15;
    const int rq   = (lane >> 4) * 4;
#pragma unroll
    for (int r = 0; r < 4; ++r) {
        int m = m0 + rq + r;
        float dm = dvec[b * NN + m];
#pragma unroll
        for (int nb = 0; nb < 8; ++nb) {
            int o = nb * 16 + col0;
            yt[((size_t)b * 128 + o) * NN + m] = (__bf16)(acc[nb][r] * dm);
        }
    }
}

// ---------------- K3: staged GEMM, 3-deep glds pipeline ------------------
// Block 256 thr: 32 rows x 128 cols; wave w: rows (w&1)*16, cols (w>>1)*64.
// grid 512 (2 blocks/CU), b = blockIdx.x & 7.

// Body KT: wait WAITSTR, barrier, ds_read buf[KT&3], cvt A(KT) from set S,
//          issue A(KT+2) into set S, issue G(KT+3) into buf[(KT+3)&3], MFMA.
#define GBODY(KT, S, DO_A, DO_G, WAITSTR)                                    \
  do {                                                                       \
    asm volatile("s_waitcnt vmcnt(" WAITSTR ")" ::: "memory");               \
    __builtin_amdgcn_sched_barrier(0);                                       \
    __builtin_amdgcn_s_barrier();                                            \
    __builtin_amdgcn_sched_barrier(0);                                       \
    const int cur_ = (KT) & 3;                                               \
    bf16x8 bv0 = *(const bf16x8*)(&sB[cur_][csel +  0 + l15][kgrp]);         \
    bf16x8 bv1 = *(const bf16x8*)(&sB[cur_][csel + 16 + l15][kgrp]);         \
    bf16x8 bv2 = *(const bf16x8*)(&sB[cur_][csel + 32 + l15][kgrp]);         \
    bf16x8 bv3 = *(const bf16x8*)(&sB[cur_][csel + 48 + l15][kgrp]);         \
    bf16x8 af;                                                               \
    af[0] = (__bf16)pa0_##S.x; af[1] = (__bf16)pa0_##S.y;                    \
    af[2] = (__bf16)pa0_##S.z; af[3] = (__bf16)pa0_##S.w;                    \
    af[4] = (__bf16)pa1_##S.x; af[5] = (__bf16)pa1_##S.y;                    \
    af[6] = (__bf16)pa1_##S.z; af[7] = (__bf16)pa1_##S.w;                    \
    __builtin_amdgcn_sched_barrier(0);                                       \
    if (DO_A) {                                                              \
      pa0_##S = *(const f32x4*)(ap + ((KT) + 2) * 32);                       \
      pa1_##S = *(const f32x4*)(ap + ((KT) + 2) * 32 + 4);                   \
    }                                                                        \
    __builtin_amdgcn_sched_barrier(0);                                       \
    if (DO_G) {                                                              \
      const __bf16* bs_ = b_src + (size_t)((KT) + 3) * 32;                   \
      load_lds16(&sB[((KT) + 3) & 3][b_row0][0], bs_);                       \
      load_lds16(&sB[((KT) + 3) & 3][b_row0 + 16][0], bs_ + (size_t)16 * NN);\
    }                                                                        \
    __builtin_amdgcn_sched_barrier(0);                                       \
    acc[0] = __builtin_amdgcn_mfma_f32_16x16x32_bf16(af, bv0, acc[0], 0, 0, 0); \
    acc[1] = __builtin_amdgcn_mfma_f32_16x16x32_bf16(af, bv1, acc[1], 0, 0, 0); \
    acc[2] = __builtin_amdgcn_mfma_f32_16x16x32_bf16(af, bv2, acc[2], 0, 0, 0); \
    acc[3] = __builtin_amdgcn_mfma_f32_16x16x32_bf16(af, bv3, acc[3], 0, 0, 0); \
  } while (0)

__global__ __launch_bounds__(256) void gemm_kernel(const float* __restrict__ adj,
                                                   const __bf16* __restrict__ yt,
                                                   const float* __restrict__ dvec,
                                                   float* __restrict__ out) {
    __shared__ alignas(16) __bf16 sB[4][128][32];   // 32 KB, 4-deep

    const int tid  = threadIdx.x;
    const int wave = tid >> 6;
    const int lane = tid & 63;
    const int b    = blockIdx.x & 7;
    const int tile = blockIdx.x >> 3;            // 0..63
    const int rsel = (wave & 1) * 16;
    const int csel = (wave >> 1) * 64;
    const int kgrp = (lane >> 4) * 8;
    const int l15  = lane & 15;

    // A: direct from global fp32, k-contiguous fragment
    const int arow_loc = tile * 32 + rsel + l15;
    const float* ap = adj + ((size_t)b * NN + arow_loc) * NN + kgrp;

    const __bf16* ytb = yt + (size_t)b * 128 * NN;
    const int b_row0 = wave * 32;
    const __bf16* b_src = ytb + (size_t)(b_row0 + (lane >> 2)) * NN + (lane & 3) * 8;

    f32x4 acc[4];
#pragma unroll
    for (int i = 0; i < 4; ++i) acc[i] = (f32x4){0.f, 0.f, 0.f, 0.f};

    f32x4 pa0_0, pa1_0, pa0_1, pa1_1;

    // prologue — issue order (pinned): G0, A0, G1, A1, G2  -> 10 outstanding
    load_lds16(&sB[0][b_row0][0], b_src);
    load_lds16(&sB[0][b_row0 + 16][0], b_src + (size_t)16 * NN);
    __builtin_amdgcn_sched_barrier(0);
    pa0_0 = *(const f32x4*)(ap);
    pa1_0 = *(const f32x4*)(ap + 4);
    __builtin_amdgcn_sched_barrier(0);
    load_lds16(&sB[1][b_row0][0], b_src + 32);
    load_lds16(&sB[1][b_row0 + 16][0], b_src + (size_t)16 * NN + 32);
    __builtin_amdgcn_sched_barrier(0);
    pa0_1 = *(const f32x4*)(ap + 32);
    pa1_1 = *(const f32x4*)(ap + 36);
    __builtin_amdgcn_sched_barrier(0);
    load_lds16(&sB[2][b_row0][0], b_src + 64);
    load_lds16(&sB[2][b_row0 + 16][0], b_src + (size_t)16 * NN + 64);
    __builtin_amdgcn_sched_barrier(0);

    for (int kt = 0; kt < 60; kt += 2) {
        GBODY(kt,     0, 1, 1, "6");
        GBODY(kt + 1, 1, 1, 1, "6");
    }
    GBODY(60, 0, 1, 1, "6");
    GBODY(61, 1, 1, 0, "6");   // A63 issued, no G64
    GBODY(62, 0, 0, 0, "4");
    GBODY(63, 1, 0, 0, "0");

    // epilogue: diag correction + row scale + relu
    //   out = d[n] * (acc + (1 - adj[n,n]) * yt[o][n])
    const int rq = (lane >> 4) * 4;
#pragma unroll
    for (int r = 0; r < 4; ++r) {
        int n_loc = tile * 32 + rsel + rq + r;
        size_t grow = (size_t)b * NN + n_loc;
        float dn   = dvec[grow];
        float cfac = 1.0f - adj[grow * NN + n_loc];
#pragma unroll
        for (int nb = 0; nb < 4; ++nb) {
            int o = csel + nb * 16 + l15;
            float yp = (float)ytb[(size_t)o * NN + n_loc];
            float v = (acc[nb][r] + cfac * yp) * dn;
            out[grow * 128 + o] = v > 0.f ? v : 0.f;
        }
    }
}

extern "C" void kernel_launch(void* const* d_in, const int* in_sizes, int n_in,
                              void* d_out, int out_size, void* d_ws, size_t ws_size,
                              hipStream_t stream) {
    const float* x   = (const float*)d_in[0];   // [8,2048,128]
    const float* adj = (const float*)d_in[1];   // [8,2048,2048]
    const float* W   = (const float*)d_in[2];   // [128,128]
    float* out = (float*)d_out;

    char* ws = (char*)d_ws;
    float*  dvec = (float*)ws;                          // 64 KB
    __bf16* Wt   = (__bf16*)(ws + (64 << 10));          // 32 KB
    __bf16* yt   = (__bf16*)(ws + (128 << 10));         // 4 MB  [B][128][2048]

    hipLaunchKernelGGL(d_kernel, dim3(NB * NN / 4 + 64), dim3(256), 0, stream,
                       adj, dvec, W, Wt);
    hipLaunchKernelGGL(xw_kernel, dim3(256), dim3(256), 0, stream, x, Wt, dvec, yt);
    hipLaunchKernelGGL(gemm_kernel, dim3(512), dim3(256), 0, stream,
                       adj, yt, dvec, out);
}